// Round 2
// baseline (356.518 us; speedup 1.0000x reference)
//
#include <hip/hip_runtime.h>
#include <hip/hip_bf16.h>

typedef __attribute__((ext_vector_type(8))) short short8;
typedef __attribute__((ext_vector_type(4))) float floatx4;

#define SCALE 0.17677669529663687f  /* 1/sqrt(32) */

__device__ __forceinline__ unsigned short f2bf(float f) {
  unsigned int x = __float_as_uint(f);
  x += 0x7fffu + ((x >> 16) & 1u);   // RNE
  return (unsigned short)(x >> 16);
}
__device__ __forceinline__ float bf2f(unsigned short u) {
  return __uint_as_float(((unsigned int)u) << 16);
}

// load 8 consecutive floats, convert to bf16 MFMA frag
__device__ __forceinline__ short8 load_cvt8(const float* p) {
  floatx4 a = *(const floatx4*)p;
  floatx4 b = *(const floatx4*)(p + 4);
  short8 r;
  r[0] = (short)f2bf(a[0]); r[1] = (short)f2bf(a[1]);
  r[2] = (short)f2bf(a[2]); r[3] = (short)f2bf(a[3]);
  r[4] = (short)f2bf(b[0]); r[5] = (short)f2bf(b[1]);
  r[6] = (short)f2bf(b[2]); r[7] = (short)f2bf(b[3]);
  return r;
}

__device__ __forceinline__ float block_sum(float v, float* red) {
  #pragma unroll
  for (int off = 32; off >= 1; off >>= 1) v += __shfl_xor(v, off, 64);
  __syncthreads();                       // protect red reuse from previous call
  if ((threadIdx.x & 63) == 0) red[threadIdx.x >> 6] = v;
  __syncthreads();
  return red[0] + red[1] + red[2] + red[3];
}

// ---------------- setup: q_p -> u_p_t[8][256] (bf16), segment offsets ----------------
__global__ __launch_bounds__(256) void setup_kernel(
    const float* __restrict__ seed,
    const float* __restrict__ Wq_p,
    const float* __restrict__ Wk_p,
    const int* __restrict__ port_batch,
    unsigned short* __restrict__ u_p_t,
    int* __restrict__ seg_start, int T, int B)
{
  __shared__ float seed_l[256];
  __shared__ float q_p[256];
  int tid = threadIdx.x;
  seed_l[tid] = seed[tid];
  __syncthreads();
  float acc = 0.f;
  for (int d = 0; d < 256; ++d) acc += seed_l[d] * Wq_p[d * 256 + tid];
  q_p[tid] = acc;
  __syncthreads();
  float hs[8];
  #pragma unroll
  for (int h = 0; h < 8; ++h) hs[h] = 0.f;
  #pragma unroll
  for (int c = 0; c < 32; ++c) {
    floatx4 wa = *(const floatx4*)(Wk_p + (size_t)tid * 256 + c * 8);
    floatx4 wb = *(const floatx4*)(Wk_p + (size_t)tid * 256 + c * 8 + 4);
    const int h = c >> 2;
    #pragma unroll
    for (int j = 0; j < 4; ++j) hs[h] += wa[j] * q_p[c * 8 + j];
    #pragma unroll
    for (int j = 0; j < 4; ++j) hs[h] += wb[j] * q_p[c * 8 + 4 + j];
  }
  #pragma unroll
  for (int h = 0; h < 8; ++h) u_p_t[h * 256 + tid] = f2bf(hs[h]);
  // lower_bound per batch id (port_batch is sorted)
  for (int b = tid; b <= B; b += 256) {
    int lo = 0, hi = T;
    while (lo < hi) { int mid = (lo + hi) >> 1; if (port_batch[mid] < b) lo = mid + 1; else hi = mid; }
    seg_start[b] = lo;
  }
}

// ---------------- main: one workgroup per segment ----------------
__global__ __launch_bounds__(256, 1) void main_kernel(
    const float* __restrict__ node,
    const int* __restrict__ tgt_idx,
    const int* __restrict__ port_index,
    const float* __restrict__ port_weight,
    const float* __restrict__ Wq_c,
    const float* __restrict__ Wk_c,
    const float* __restrict__ Wv_p,
    const float* __restrict__ Wo_p,
    const float* __restrict__ Wv_c,
    const float* __restrict__ Wo_c,
    const float* __restrict__ ln_g,
    const float* __restrict__ ln_b,
    const float* __restrict__ fuse_W1,
    const float* __restrict__ fuse_b1,
    const float* __restrict__ fuse_W2,
    const float* __restrict__ fuse_b2,
    const float* __restrict__ head_W1,
    const float* __restrict__ head_b1,
    const float* __restrict__ head_W2,
    const float* __restrict__ head_b2,
    const unsigned short* __restrict__ u_p_t,
    const int* __restrict__ seg_start,
    float* __restrict__ out, int T)
{
  // overlay region: token tile (attention) then finalize scratch
  __shared__ __align__(16) char ovl[33792];          // 64 x 264 bf16
  __shared__ __align__(16) unsigned short E_t[16 * 72];
  __shared__ __align__(16) unsigned short u_all[16 * 264];
  __shared__ float tgt_l[256];
  __shared__ float q_c_l[256];
  __shared__ float l_lds[16];
  __shared__ float red_l[4];

  unsigned short* tok_lds = (unsigned short*)ovl;
  float* s_lds    = (float*)ovl;                     // 16*257*4 = 16448
  float* pooled_l = (float*)(ovl + 16448);           // 256 f
  float* att_l    = (float*)(ovl + 17472);           // 256 f
  float* z_l      = (float*)(ovl + 18496);           // 768 f
  float* zn_l     = (float*)(ovl + 21568);           // 768 f
  float* h1_l     = (float*)(ovl + 24640);           // 256 f
  float* z2_l     = (float*)(ovl + 25664);           // 256 f
  float* hh_l     = (float*)(ovl + 26688);           // 256 f

  const int tid  = threadIdx.x;
  const int b    = blockIdx.x;
  const int lane = tid & 63;
  const int w    = tid >> 6;      // wave id 0..3
  const int q    = lane >> 4;     // quad 0..3
  const int n    = lane & 15;

  // ---- preamble: tgt row, q_c = tgt@Wq_c, u_c folded, u_all assembled ----
  const int tix = tgt_idx[b];
  tgt_l[tid] = node[(size_t)tix * 256 + tid];
  if (tid < 16) l_lds[tid] = 0.f;
  __syncthreads();
  {
    float acc = 0.f;
    for (int d = 0; d < 256; ++d) acc += tgt_l[d] * Wq_c[d * 256 + tid];
    q_c_l[tid] = acc;
  }
  __syncthreads();
  {
    const int cn = tid >> 5, ch = (tid & 31) * 8;    // copy u_p rows 0..7 (bf16)
    *(short8*)(u_all + cn * 264 + ch) = *(const short8*)(u_p_t + cn * 256 + ch);
    float hs[8];
    #pragma unroll
    for (int h = 0; h < 8; ++h) hs[h] = 0.f;
    #pragma unroll
    for (int c = 0; c < 32; ++c) {
      floatx4 wa = *(const floatx4*)(Wk_c + (size_t)tid * 256 + c * 8);
      floatx4 wb = *(const floatx4*)(Wk_c + (size_t)tid * 256 + c * 8 + 4);
      const int h = c >> 2;
      #pragma unroll
      for (int j = 0; j < 4; ++j) hs[h] += wa[j] * q_c_l[c * 8 + j];
      #pragma unroll
      for (int j = 0; j < 4; ++j) hs[h] += wb[j] * q_c_l[c * 8 + 4 + j];
    }
    #pragma unroll
    for (int h = 0; h < 8; ++h) u_all[(8 + h) * 264 + tid] = f2bf(hs[h]);
  }
  __syncthreads();

  // persistent B-frags: U[k][col], col 0..7 = u_p heads, 8..15 = u_c heads
  short8 ufrag[8];
  #pragma unroll
  for (int s = 0; s < 8; ++s)
    ufrag[s] = *(const short8*)(u_all + n * 264 + q * 8 + s * 32);

  const int start  = seg_start[b];
  const int end    = seg_start[b + 1];
  const int ntiles = (end - start + 63) >> 6;

  floatx4 sacc[4];
  #pragma unroll
  for (int nt = 0; nt < 4; ++nt) sacc[nt] = (floatx4){0.f, 0.f, 0.f, 0.f};

  short8 cur[8], nxt[8];
  float pwc[4], pwn[4];

  if (ntiles > 0) {
    int t = start + w * 16 + n; int tc = t < T ? t : T - 1;
    const float* rp = node + (size_t)port_index[tc] * 256 + q * 8;
    #pragma unroll
    for (int s = 0; s < 8; ++s) cur[s] = load_cvt8(rp + s * 32);
    #pragma unroll
    for (int r = 0; r < 4; ++r) { int tr = start + w * 16 + q * 4 + r; pwc[r] = port_weight[tr < T ? tr : T - 1]; }
  }

  for (int it = 0; it < ntiles; ++it) {
    const int tbase = start + it * 64;
    if (it + 1 < ntiles) {   // prefetch next tile
      int t = tbase + 64 + w * 16 + n; int tc = t < T ? t : T - 1;
      const float* rp = node + (size_t)port_index[tc] * 256 + q * 8;
      #pragma unroll
      for (int s = 0; s < 8; ++s) nxt[s] = load_cvt8(rp + s * 32);
      #pragma unroll
      for (int r = 0; r < 4; ++r) { int tr = tbase + 64 + w * 16 + q * 4 + r; pwn[r] = port_weight[tr < T ? tr : T - 1]; }
    }
    // phase 1: logits = tok_tile[16x256] @ U[256x16]
    floatx4 lacc = (floatx4){0.f, 0.f, 0.f, 0.f};
    #pragma unroll
    for (int s = 0; s < 8; ++s)
      lacc = __builtin_amdgcn_mfma_f32_16x16x32_bf16(cur[s], ufrag[s], lacc, 0, 0, 0);
    float lsum = 0.f;
    #pragma unroll
    for (int r = 0; r < 4; ++r) {
      const int tr = tbase + w * 16 + q * 4 + r;   // D row = quad*4+r
      float e = 0.f;
      if (tr < end) {
        float lg = lacc[r] * SCALE + logf(pwc[r] + 1e-8f);
        e = __expf(lg);
      }
      unsigned short eb = f2bf(e);
      E_t[n * 72 + w * 16 + q * 4 + r] = eb;       // E^T: [col][token]
      lsum += bf2f(eb);                            // denominator consistent with bf16 e
    }
    lsum += __shfl_xor(lsum, 16, 64);
    lsum += __shfl_xor(lsum, 32, 64);
    if (lane < 16) atomicAdd(&l_lds[lane], lsum);
    #pragma unroll
    for (int s = 0; s < 8; ++s)                    // tok tile row-major bf16 -> LDS
      *(short8*)(tok_lds + (w * 16 + n) * 264 + q * 8 + s * 32) = cur[s];
    __syncthreads();
    // phase 2: s[16 cols][256 d] += E^T[16x64] @ tok[64x256], wave w owns d in [w*64, w*64+64)
    short8 ea0 = *(const short8*)(E_t + n * 72 + q * 8);
    short8 ea1 = *(const short8*)(E_t + n * 72 + 32 + q * 8);
    #pragma unroll
    for (int nt = 0; nt < 4; ++nt) {
      const int dcol = w * 64 + nt * 16 + n;
      short8 b0, b1;
      #pragma unroll
      for (int j = 0; j < 8; ++j) b0[j] = (short)tok_lds[(q * 8 + j) * 264 + dcol];
      #pragma unroll
      for (int j = 0; j < 8; ++j) b1[j] = (short)tok_lds[(32 + q * 8 + j) * 264 + dcol];
      sacc[nt] = __builtin_amdgcn_mfma_f32_16x16x32_bf16(ea0, b0, sacc[nt], 0, 0, 0);
      sacc[nt] = __builtin_amdgcn_mfma_f32_16x16x32_bf16(ea1, b1, sacc[nt], 0, 0, 0);
    }
    __syncthreads();
    #pragma unroll
    for (int s = 0; s < 8; ++s) cur[s] = nxt[s];
    #pragma unroll
    for (int r = 0; r < 4; ++r) pwc[r] = pwn[r];
  }

  // ---- finalize: normalize weighted sums into s_lds[16][257] ----
  {
    float inv[4];
    #pragma unroll
    for (int r = 0; r < 4; ++r) inv[r] = 1.0f / (l_lds[q * 4 + r] + 1e-9f);
    #pragma unroll
    for (int nt = 0; nt < 4; ++nt) {
      #pragma unroll
      for (int r = 0; r < 4; ++r)
        s_lds[(q * 4 + r) * 257 + w * 64 + nt * 16 + n] = sacc[nt][r] * inv[r];
    }
  }
  __syncthreads();
  // pooled = (n_p @ Wv_p per head), att likewise with Wv_c
  {
    const int h = tid >> 5;
    float po = 0.f, ao = 0.f;
    for (int d = 0; d < 256; ++d) {
      po += s_lds[h * 257 + d]       * Wv_p[d * 256 + tid];
      ao += s_lds[(8 + h) * 257 + d] * Wv_c[d * 256 + tid];
    }
    pooled_l[tid] = po;
    att_l[tid] = ao;
  }
  __syncthreads();
  // contexts = pooled @ Wo_p ; fused = tgt + att @ Wo_c ; z = [tgt|contexts|fused]
  {
    float cx = 0.f, at2 = 0.f;
    for (int o = 0; o < 256; ++o) {
      cx  += pooled_l[o] * Wo_p[o * 256 + tid];
      at2 += att_l[o]    * Wo_c[o * 256 + tid];
    }
    const float tg = tgt_l[tid];
    z_l[tid]       = tg;
    z_l[256 + tid] = cx;
    z_l[512 + tid] = tg + at2;
  }
  __syncthreads();
  // LayerNorm(768)
  const float z0 = z_l[tid], z1 = z_l[256 + tid], z2v = z_l[512 + tid];
  const float mu = block_sum(z0 + z1 + z2v, red_l) * (1.0f / 768.0f);
  const float d0 = z0 - mu, d1 = z1 - mu, d2 = z2v - mu;
  const float var = block_sum(d0 * d0 + d1 * d1 + d2 * d2, red_l) * (1.0f / 768.0f);
  const float rstd = 1.0f / sqrtf(var + 1e-5f);
  zn_l[tid]       = d0 * rstd * ln_g[tid]       + ln_b[tid];
  zn_l[256 + tid] = d1 * rstd * ln_g[256 + tid] + ln_b[256 + tid];
  zn_l[512 + tid] = d2 * rstd * ln_g[512 + tid] + ln_b[512 + tid];
  __syncthreads();
  // fuse MLP
  {
    float a1 = fuse_b1[tid];
    for (int i = 0; i < 768; ++i) a1 += zn_l[i] * fuse_W1[i * 256 + tid];
    h1_l[tid] = fmaxf(a1, 0.f);
  }
  __syncthreads();
  {
    float a2 = fuse_b2[tid];
    for (int i = 0; i < 256; ++i) a2 += h1_l[i] * fuse_W2[i * 256 + tid];
    z2_l[tid] = a2;
  }
  __syncthreads();
  // quantile heads
  {
    float a3 = head_b1[tid];
    for (int i = 0; i < 256; ++i) a3 += z2_l[i] * head_W1[i * 256 + tid];
    hh_l[tid] = fmaxf(a3, 0.f);
  }
  __syncthreads();
  #pragma unroll
  for (int q2 = 0; q2 < 3; ++q2) {
    float p = hh_l[tid] * head_W2[tid * 3 + q2];
    float tot = block_sum(p, red_l);
    if (tid == 0) out[b * 3 + q2] = tot + head_b2[q2];
  }
}

extern "C" void kernel_launch(void* const* d_in, const int* in_sizes, int n_in,
                              void* d_out, int out_size, void* d_ws, size_t ws_size,
                              hipStream_t stream) {
  const float* node        = (const float*)d_in[0];
  const int*   tgt_idx     = (const int*)d_in[1];
  const int*   port_index  = (const int*)d_in[2];
  const int*   port_batch  = (const int*)d_in[3];
  const float* port_weight = (const float*)d_in[4];
  const float* seed        = (const float*)d_in[5];
  const float* Wq_p = (const float*)d_in[6];
  const float* Wk_p = (const float*)d_in[7];
  const float* Wv_p = (const float*)d_in[8];
  const float* Wo_p = (const float*)d_in[9];
  const float* Wq_c = (const float*)d_in[10];
  const float* Wk_c = (const float*)d_in[11];
  const float* Wv_c = (const float*)d_in[12];
  const float* Wo_c = (const float*)d_in[13];
  const float* ln_g = (const float*)d_in[14];
  const float* ln_b = (const float*)d_in[15];
  const float* fuse_W1 = (const float*)d_in[16];
  const float* fuse_b1 = (const float*)d_in[17];
  const float* fuse_W2 = (const float*)d_in[18];
  const float* fuse_b2 = (const float*)d_in[19];
  const float* head_W1 = (const float*)d_in[20];
  const float* head_b1 = (const float*)d_in[21];
  const float* head_W2 = (const float*)d_in[22];
  const float* head_b2 = (const float*)d_in[23];

  const int B = in_sizes[1];
  const int T = in_sizes[2];

  unsigned short* u_p_t = (unsigned short*)d_ws;                 // 8*256 bf16 = 4096 B
  int* seg = (int*)((char*)d_ws + 4096);                         // (B+1) ints

  setup_kernel<<<1, 256, 0, stream>>>(seed, Wq_p, Wk_p, port_batch, u_p_t, seg, T, B);
  main_kernel<<<B, 256, 0, stream>>>(node, tgt_idx, port_index, port_weight,
      Wq_c, Wk_c, Wv_p, Wo_p, Wv_c, Wo_c, ln_g, ln_b,
      fuse_W1, fuse_b1, fuse_W2, fuse_b2, head_W1, head_b1, head_W2, head_b2,
      u_p_t, seg, (float*)d_out, T);
}

// Round 3
// 320.737 us; speedup vs baseline: 1.1116x; 1.1116x over previous
//
#include <hip/hip_runtime.h>
#include <hip/hip_bf16.h>

typedef __attribute__((ext_vector_type(8))) short short8;
typedef __attribute__((ext_vector_type(4))) float floatx4;

#define SCALE 0.17677669529663687f  /* 1/sqrt(32) */

__device__ __forceinline__ unsigned short f2bf(float f) {
  unsigned int x = __float_as_uint(f);
  x += 0x7fffu + ((x >> 16) & 1u);   // RNE
  return (unsigned short)(x >> 16);
}
__device__ __forceinline__ float bf2f(unsigned short u) {
  return __uint_as_float(((unsigned int)u) << 16);
}

// load 8 consecutive floats, convert to bf16 MFMA frag
__device__ __forceinline__ short8 load_cvt8(const float* p) {
  floatx4 a = *(const floatx4*)p;
  floatx4 b = *(const floatx4*)(p + 4);
  short8 r;
  r[0] = (short)f2bf(a[0]); r[1] = (short)f2bf(a[1]);
  r[2] = (short)f2bf(a[2]); r[3] = (short)f2bf(a[3]);
  r[4] = (short)f2bf(b[0]); r[5] = (short)f2bf(b[1]);
  r[6] = (short)f2bf(b[2]); r[7] = (short)f2bf(b[3]);
  return r;
}

__device__ __forceinline__ float block_sum(float v, float* red) {
  #pragma unroll
  for (int off = 32; off >= 1; off >>= 1) v += __shfl_xor(v, off, 64);
  __syncthreads();
  if ((threadIdx.x & 63) == 0) red[threadIdx.x >> 6] = v;
  __syncthreads();
  return red[0] + red[1] + red[2] + red[3];
}

// K-split coalesced matvec: out[0..255] = act[0..255] @ W[256x256], weights dwordx4.
// tid = kg(2b)<<6 | c4(6b); each thread: cols 4*c4..+3, k in [kg*64, kg*64+64).
__device__ __forceinline__ void matvec256(const float* __restrict__ W,
                                          const float* act, float* outv,
                                          float* red4, int tid) {
  const int c4 = tid & 63, kg = tid >> 6, c0 = c4 * 4;
  floatx4 acc = (floatx4){0.f, 0.f, 0.f, 0.f};
  const float* Wp = W + (size_t)(kg * 64) * 256 + c0;
  const float* ap = act + kg * 64;
  #pragma unroll 8
  for (int k = 0; k < 64; ++k) {
    floatx4 wv = *(const floatx4*)(Wp + (size_t)k * 256);
    float a = ap[k];
    acc[0] += a * wv[0]; acc[1] += a * wv[1];
    acc[2] += a * wv[2]; acc[3] += a * wv[3];
  }
  *(floatx4*)(red4 + kg * 256 + c0) = acc;
  __syncthreads();
  outv[tid] = red4[tid] + red4[256 + tid] + red4[512 + tid] + red4[768 + tid];
  __syncthreads();
}

// ---------------- setup: per-b q_c + u_c fold; WG0 also u_p; seg boundaries ----------------
__global__ __launch_bounds__(256) void setup_kernel(
    const float* __restrict__ node,
    const int* __restrict__ tgt_idx,
    const int* __restrict__ port_batch,
    const float* __restrict__ seed,
    const float* __restrict__ Wq_p,
    const float* __restrict__ Wk_p,
    const float* __restrict__ Wq_c,
    const float* __restrict__ Wk_c,
    unsigned short* __restrict__ u_p_t,
    unsigned short* __restrict__ u_c_all,
    int* __restrict__ seg, int T, int B)
{
  __shared__ float act_l[256];
  __shared__ float q_l[256];
  __shared__ __align__(16) float red4[1024];
  const int tid = threadIdx.x;
  const int b = blockIdx.x;

  // segment boundaries (sorted port_batch lower_bound)
  if (tid == 0 || (tid == 64 && b == B - 1)) {
    int key = (tid == 0) ? b : B;
    int lo = 0, hi = T;
    while (lo < hi) { int mid = (lo + hi) >> 1; if (port_batch[mid] < key) lo = mid + 1; else hi = mid; }
    seg[key] = lo;
  }

  // q_c[b] = tgt @ Wq_c
  act_l[tid] = node[(size_t)tgt_idx[b] * 256 + tid];
  __syncthreads();
  matvec256(Wq_c, act_l, q_l, red4, tid);

  // u_c[b][h][d=tid] = sum_dh Wk_c[tid, h*32+dh] * q_c[h*32+dh]  (bf16 out)
  {
    float hs[8];
    #pragma unroll
    for (int h = 0; h < 8; ++h) hs[h] = 0.f;
    #pragma unroll
    for (int c = 0; c < 32; ++c) {
      floatx4 wa = *(const floatx4*)(Wk_c + (size_t)tid * 256 + c * 8);
      floatx4 wb = *(const floatx4*)(Wk_c + (size_t)tid * 256 + c * 8 + 4);
      const int h = c >> 2;
      #pragma unroll
      for (int j = 0; j < 4; ++j) hs[h] += wa[j] * q_l[c * 8 + j];
      #pragma unroll
      for (int j = 0; j < 4; ++j) hs[h] += wb[j] * q_l[c * 8 + 4 + j];
    }
    #pragma unroll
    for (int h = 0; h < 8; ++h)
      u_c_all[(size_t)b * 2048 + h * 256 + tid] = f2bf(hs[h]);
  }

  // WG0: u_p from seed
  if (b == 0) {
    __syncthreads();
    act_l[tid] = seed[tid];
    __syncthreads();
    matvec256(Wq_p, act_l, q_l, red4, tid);
    float hs[8];
    #pragma unroll
    for (int h = 0; h < 8; ++h) hs[h] = 0.f;
    #pragma unroll
    for (int c = 0; c < 32; ++c) {
      floatx4 wa = *(const floatx4*)(Wk_p + (size_t)tid * 256 + c * 8);
      floatx4 wb = *(const floatx4*)(Wk_p + (size_t)tid * 256 + c * 8 + 4);
      const int h = c >> 2;
      #pragma unroll
      for (int j = 0; j < 4; ++j) hs[h] += wa[j] * q_l[c * 8 + j];
      #pragma unroll
      for (int j = 0; j < 4; ++j) hs[h] += wb[j] * q_l[c * 8 + 4 + j];
    }
    #pragma unroll
    for (int h = 0; h < 8; ++h) u_p_t[h * 256 + tid] = f2bf(hs[h]);
  }
}

// ---------------- attention: WG (s, b) handles tiles s, s+S, ... of segment b ----------------
__global__ __launch_bounds__(256, 3) void attn_kernel(
    const float* __restrict__ node,
    const int* __restrict__ port_index,
    const float* __restrict__ port_weight,
    const unsigned short* __restrict__ u_p_t,
    const unsigned short* __restrict__ u_c_all,
    const int* __restrict__ seg,
    float* __restrict__ slabs, int T, int S)
{
  __shared__ __align__(16) unsigned short tok_lds[64 * 264];
  __shared__ __align__(16) unsigned short E_t[16 * 72];
  __shared__ float l_lds[16];

  const int tid  = threadIdx.x;
  const int s    = blockIdx.x;
  const int b    = blockIdx.y;
  const int lane = tid & 63;
  const int w    = tid >> 6;
  const int q    = lane >> 4;
  const int n    = lane & 15;

  if (tid < 16) l_lds[tid] = 0.f;

  // persistent B-frags: col n<8 -> u_p head n, n>=8 -> u_c[b] head n-8
  short8 ufrag[8];
  const unsigned short* ubase = (n < 8) ? (u_p_t + n * 256)
                                        : (u_c_all + (size_t)b * 2048 + (n - 8) * 256);
  #pragma unroll
  for (int s8 = 0; s8 < 8; ++s8)
    ufrag[s8] = *(const short8*)(ubase + q * 8 + s8 * 32);

  const int start  = seg[b];
  const int end    = seg[b + 1];
  const int ntiles = (end - start + 63) >> 6;

  floatx4 sacc[4];
  #pragma unroll
  for (int nt = 0; nt < 4; ++nt) sacc[nt] = (floatx4){0.f, 0.f, 0.f, 0.f};

  short8 cur[8], nxt[8];
  float pwc[4], pwn[4];

  __syncthreads();   // l_lds init visible to all waves

  if (s < ntiles) {
    int t = start + s * 64 + w * 16 + n; int tc = t < T ? t : T - 1;
    const float* rp = node + (size_t)port_index[tc] * 256 + q * 8;
    #pragma unroll
    for (int k = 0; k < 8; ++k) cur[k] = load_cvt8(rp + k * 32);
    #pragma unroll
    for (int r = 0; r < 4; ++r) { int tr = start + s * 64 + w * 16 + q * 4 + r; pwc[r] = port_weight[tr < T ? tr : T - 1]; }
  }

  for (int it = s; it < ntiles; it += S) {
    const int tbase = start + it * 64;
    if (it + S < ntiles) {   // prefetch next owned tile
      int t = start + (it + S) * 64 + w * 16 + n; int tc = t < T ? t : T - 1;
      const float* rp = node + (size_t)port_index[tc] * 256 + q * 8;
      #pragma unroll
      for (int k = 0; k < 8; ++k) nxt[k] = load_cvt8(rp + k * 32);
      #pragma unroll
      for (int r = 0; r < 4; ++r) { int tr = start + (it + S) * 64 + w * 16 + q * 4 + r; pwn[r] = port_weight[tr < T ? tr : T - 1]; }
    }
    // phase 1: logits = tok_tile[64x256] @ U[256x16] (per wave: 16 tokens)
    floatx4 lacc = (floatx4){0.f, 0.f, 0.f, 0.f};
    #pragma unroll
    for (int k = 0; k < 8; ++k)
      lacc = __builtin_amdgcn_mfma_f32_16x16x32_bf16(cur[k], ufrag[k], lacc, 0, 0, 0);
    float lsum = 0.f;
    #pragma unroll
    for (int r = 0; r < 4; ++r) {
      const int tr = tbase + w * 16 + q * 4 + r;   // token = D-layout row
      float e = 0.f;
      if (tr < end) {
        float lg = lacc[r] * SCALE + logf(pwc[r] + 1e-8f);
        e = __expf(lg);
      }
      unsigned short eb = f2bf(e);
      E_t[n * 72 + w * 16 + q * 4 + r] = eb;       // E^T: [col][token]
      lsum += bf2f(eb);                            // denom consistent with bf16 e
    }
    lsum += __shfl_xor(lsum, 16, 64);
    lsum += __shfl_xor(lsum, 32, 64);
    if (lane < 16) atomicAdd(&l_lds[lane], lsum);
    #pragma unroll
    for (int k = 0; k < 8; ++k)                    // tok tile row-major bf16 -> LDS
      *(short8*)(tok_lds + (w * 16 + n) * 264 + q * 8 + k * 32) = cur[k];
    __syncthreads();
    // phase 2: sums[16 cols][256 d] += E^T[16x64] @ tok[64x256]; wave w owns d slice
    short8 ea0 = *(const short8*)(E_t + n * 72 + q * 8);
    short8 ea1 = *(const short8*)(E_t + n * 72 + 32 + q * 8);
    #pragma unroll
    for (int nt = 0; nt < 4; ++nt) {
      const int dcol = w * 64 + nt * 16 + n;
      short8 b0, b1;
      #pragma unroll
      for (int j = 0; j < 8; ++j) b0[j] = (short)tok_lds[(q * 8 + j) * 264 + dcol];
      #pragma unroll
      for (int j = 0; j < 8; ++j) b1[j] = (short)tok_lds[(32 + q * 8 + j) * 264 + dcol];
      sacc[nt] = __builtin_amdgcn_mfma_f32_16x16x32_bf16(ea0, b0, sacc[nt], 0, 0, 0);
      sacc[nt] = __builtin_amdgcn_mfma_f32_16x16x32_bf16(ea1, b1, sacc[nt], 0, 0, 0);
    }
    __syncthreads();
    #pragma unroll
    for (int k = 0; k < 8; ++k) cur[k] = nxt[k];
    #pragma unroll
    for (int r = 0; r < 4; ++r) pwc[r] = pwn[r];
  }

  // write partial slab: [16 rows][256 d] + l[16]
  float* sl = slabs + ((size_t)b * S + s) * 4224;
  #pragma unroll
  for (int nt = 0; nt < 4; ++nt)
    #pragma unroll
    for (int r = 0; r < 4; ++r)
      sl[(q * 4 + r) * 256 + w * 64 + nt * 16 + n] = sacc[nt][r];
  if (tid < 16) sl[4096 + tid] = l_lds[tid];
}

// ---------------- finalize: per-b slab-sum, normalize, matvec chain ----------------
__global__ __launch_bounds__(256) void finalize_kernel(
    const float* __restrict__ node,
    const int* __restrict__ tgt_idx,
    const float* __restrict__ Wv_p,
    const float* __restrict__ Wo_p,
    const float* __restrict__ Wv_c,
    const float* __restrict__ Wo_c,
    const float* __restrict__ ln_g,
    const float* __restrict__ ln_b,
    const float* __restrict__ fuse_W1,
    const float* __restrict__ fuse_b1,
    const float* __restrict__ fuse_W2,
    const float* __restrict__ fuse_b2,
    const float* __restrict__ head_W1,
    const float* __restrict__ head_b1,
    const float* __restrict__ head_W2,
    const float* __restrict__ head_b2,
    const float* __restrict__ slabs,
    float* __restrict__ out, int S)
{
  __shared__ float s_lds[16 * 257];
  __shared__ float tgt_l[256];
  __shared__ float va[256], vb[256];
  __shared__ float z_l[768], zn_l[768];
  __shared__ __align__(16) float red4[1024];
  __shared__ float red_l[4];
  __shared__ float l_loc[16];

  const int tid = threadIdx.x;
  const int b   = blockIdx.x;
  const int c4 = tid & 63, kg = tid >> 6, c0 = c4 * 4;

  // sum partial slabs
  const float* sb = slabs + (size_t)b * S * 4224;
  for (int i = tid; i < 4096; i += 256) {
    float v = 0.f;
    for (int s = 0; s < S; ++s) v += sb[s * 4224 + i];
    s_lds[(i >> 8) * 257 + (i & 255)] = v;
  }
  if (tid < 16) {
    float v = 0.f;
    for (int s = 0; s < S; ++s) v += sb[s * 4224 + 4096 + tid];
    l_loc[tid] = v;
  }
  tgt_l[tid] = node[(size_t)tgt_idx[b] * 256 + tid];
  __syncthreads();
  #pragma unroll
  for (int r = 0; r < 16; ++r)
    s_lds[r * 257 + tid] *= 1.0f / (l_loc[r] + 1e-9f);
  __syncthreads();

  // pooled = n_p @ Wv_p, att = n_c @ Wv_c (per-head act: row = out_col>>5)
  {
    const int hrow = c0 >> 5;
    floatx4 accP = (floatx4){0.f,0.f,0.f,0.f}, accA = accP;
    const float* wp = Wv_p + (size_t)(kg * 64) * 256 + c0;
    const float* wc = Wv_c + (size_t)(kg * 64) * 256 + c0;
    const float* ap = s_lds + hrow * 257 + kg * 64;
    const float* aa = s_lds + (8 + hrow) * 257 + kg * 64;
    #pragma unroll 8
    for (int k = 0; k < 64; ++k) {
      floatx4 w1 = *(const floatx4*)(wp + (size_t)k * 256);
      floatx4 w2 = *(const floatx4*)(wc + (size_t)k * 256);
      float a1 = ap[k], a2 = aa[k];
      accP[0] += a1*w1[0]; accP[1] += a1*w1[1]; accP[2] += a1*w1[2]; accP[3] += a1*w1[3];
      accA[0] += a2*w2[0]; accA[1] += a2*w2[1]; accA[2] += a2*w2[2]; accA[3] += a2*w2[3];
    }
    *(floatx4*)(red4 + kg * 256 + c0) = accP;
    __syncthreads();
    float po = red4[tid] + red4[256 + tid] + red4[512 + tid] + red4[768 + tid];
    __syncthreads();
    *(floatx4*)(red4 + kg * 256 + c0) = accA;
    __syncthreads();
    float ao = red4[tid] + red4[256 + tid] + red4[512 + tid] + red4[768 + tid];
    va[tid] = po; vb[tid] = ao;
    __syncthreads();
  }
  // contexts = va @ Wo_p ; at2 = vb @ Wo_c ; z = [tgt | cx | tgt+at2]
  {
    floatx4 accP = (floatx4){0.f,0.f,0.f,0.f}, accA = accP;
    const float* wp = Wo_p + (size_t)(kg * 64) * 256 + c0;
    const float* wc = Wo_c + (size_t)(kg * 64) * 256 + c0;
    #pragma unroll 8
    for (int k = 0; k < 64; ++k) {
      floatx4 w1 = *(const floatx4*)(wp + (size_t)k * 256);
      floatx4 w2 = *(const floatx4*)(wc + (size_t)k * 256);
      float a1 = va[kg * 64 + k], a2 = vb[kg * 64 + k];
      accP[0] += a1*w1[0]; accP[1] += a1*w1[1]; accP[2] += a1*w1[2]; accP[3] += a1*w1[3];
      accA[0] += a2*w2[0]; accA[1] += a2*w2[1]; accA[2] += a2*w2[2]; accA[3] += a2*w2[3];
    }
    *(floatx4*)(red4 + kg * 256 + c0) = accP;
    __syncthreads();
    float cx = red4[tid] + red4[256 + tid] + red4[512 + tid] + red4[768 + tid];
    __syncthreads();
    *(floatx4*)(red4 + kg * 256 + c0) = accA;
    __syncthreads();
    float at2 = red4[tid] + red4[256 + tid] + red4[512 + tid] + red4[768 + tid];
    const float tg = tgt_l[tid];
    z_l[tid] = tg; z_l[256 + tid] = cx; z_l[512 + tid] = tg + at2;
    __syncthreads();
  }
  // LayerNorm(768)
  {
    const float z0 = z_l[tid], z1 = z_l[256 + tid], z2v = z_l[512 + tid];
    const float mu = block_sum(z0 + z1 + z2v, red_l) * (1.0f / 768.0f);
    const float d0 = z0 - mu, d1 = z1 - mu, d2 = z2v - mu;
    const float var = block_sum(d0 * d0 + d1 * d1 + d2 * d2, red_l) * (1.0f / 768.0f);
    const float rstd = 1.0f / sqrtf(var + 1e-5f);
    zn_l[tid]       = d0 * rstd * ln_g[tid]       + ln_b[tid];
    zn_l[256 + tid] = d1 * rstd * ln_g[256 + tid] + ln_b[256 + tid];
    zn_l[512 + tid] = d2 * rstd * ln_g[512 + tid] + ln_b[512 + tid];
    __syncthreads();
  }
  // h1 = relu(zn @ fuse_W1 + b1)   (K=768 -> 192/thread)
  {
    floatx4 acc = (floatx4){0.f,0.f,0.f,0.f};
    const float* wp = fuse_W1 + (size_t)(kg * 192) * 256 + c0;
    const float* ap = zn_l + kg * 192;
    #pragma unroll 8
    for (int k = 0; k < 192; ++k) {
      floatx4 wv = *(const floatx4*)(wp + (size_t)k * 256);
      float a = ap[k];
      acc[0] += a*wv[0]; acc[1] += a*wv[1]; acc[2] += a*wv[2]; acc[3] += a*wv[3];
    }
    *(floatx4*)(red4 + kg * 256 + c0) = acc;
    __syncthreads();
    va[tid] = fmaxf(red4[tid] + red4[256 + tid] + red4[512 + tid] + red4[768 + tid] + fuse_b1[tid], 0.f);
    __syncthreads();
  }
  // z2 = h1 @ fuse_W2 + b2
  matvec256(fuse_W2, va, vb, red4, tid);
  {
    vb[tid] += fuse_b2[tid];
    __syncthreads();
  }
  // hh = relu(z2 @ head_W1 + b1)
  matvec256(head_W1, vb, va, red4, tid);
  {
    va[tid] = fmaxf(va[tid] + head_b1[tid], 0.f);
    __syncthreads();
  }
  // out = hh @ head_W2 + b2
  #pragma unroll
  for (int q2 = 0; q2 < 3; ++q2) {
    float p = va[tid] * head_W2[tid * 3 + q2];
    float tot = block_sum(p, red_l);
    if (tid == 0) out[b * 3 + q2] = tot + head_b2[q2];
  }
}

extern "C" void kernel_launch(void* const* d_in, const int* in_sizes, int n_in,
                              void* d_out, int out_size, void* d_ws, size_t ws_size,
                              hipStream_t stream) {
  const float* node        = (const float*)d_in[0];
  const int*   tgt_idx     = (const int*)d_in[1];
  const int*   port_index  = (const int*)d_in[2];
  const int*   port_batch  = (const int*)d_in[3];
  const float* port_weight = (const float*)d_in[4];
  const float* seed        = (const float*)d_in[5];
  const float* Wq_p = (const float*)d_in[6];
  const float* Wk_p = (const float*)d_in[7];
  const float* Wv_p = (const float*)d_in[8];
  const float* Wo_p = (const float*)d_in[9];
  const float* Wq_c = (const float*)d_in[10];
  const float* Wk_c = (const float*)d_in[11];
  const float* Wv_c = (const float*)d_in[12];
  const float* Wo_c = (const float*)d_in[13];
  const float* ln_g = (const float*)d_in[14];
  const float* ln_b = (const float*)d_in[15];
  const float* fuse_W1 = (const float*)d_in[16];
  const float* fuse_b1 = (const float*)d_in[17];
  const float* fuse_W2 = (const float*)d_in[18];
  const float* fuse_b2 = (const float*)d_in[19];
  const float* head_W1 = (const float*)d_in[20];
  const float* head_b1 = (const float*)d_in[21];
  const float* head_W2 = (const float*)d_in[22];
  const float* head_b2 = (const float*)d_in[23];

  const int B = in_sizes[1];
  const int T = in_sizes[2];

  // ws layout
  unsigned short* u_p_t   = (unsigned short*)d_ws;                       // 4 KB
  int*            seg     = (int*)((char*)d_ws + 4096);                  // (B+1)*4
  unsigned short* u_c_all = (unsigned short*)((char*)d_ws + 8192);       // B*4096 B
  size_t slab_off = 8192 + (size_t)B * 4096;
  float* slabs = (float*)((char*)d_ws + slab_off);
  size_t per_split = (size_t)B * 4224 * 4;                               // bytes per s-slice
  int S = 1;
  if (ws_size >= slab_off + 4 * per_split) S = 4;
  else if (ws_size >= slab_off + 2 * per_split) S = 2;

  setup_kernel<<<B, 256, 0, stream>>>(node, tgt_idx, port_batch, seed,
      Wq_p, Wk_p, Wq_c, Wk_c, u_p_t, u_c_all, seg, T, B);
  attn_kernel<<<dim3(S, B), 256, 0, stream>>>(node, port_index, port_weight,
      u_p_t, u_c_all, seg, slabs, T, S);
  finalize_kernel<<<B, 256, 0, stream>>>(node, tgt_idx,
      Wv_p, Wo_p, Wv_c, Wo_c, ln_g, ln_b,
      fuse_W1, fuse_b1, fuse_W2, fuse_b2, head_W1, head_b1, head_W2, head_b2,
      slabs, (float*)d_out, S);
}